// Round 1
// baseline (1413.564 us; speedup 1.0000x reference)
//
#include <hip/hip_runtime.h>
#include <math.h>

#define Bb 8
#define Hh 512
#define N2 32
#define Ll 4096
#define CH 256
#define NCH 16

// ---------------- Stage 1: S4D kernel gen + chunked causal conv + GELU -------
// One workgroup per (b,h). Chunk-scan formulation:
//   y[cC+t] = sum_{s<=t} k[t-s] u[cC+s]  +  2 Re( sum_n Ck_n w_n^{t+1} S_n[c] )
//   S[c+1]  = w^C S[c] + sum_s w^{C-1-s} u[cC+s]
__global__ __launch_bounds__(256, 2) void s4d_stage1(
    const float* __restrict__ u,
    const float* __restrict__ log_dt,
    const float* __restrict__ C_re,
    const float* __restrict__ C_im,
    const float* __restrict__ log_A_real,
    const float* __restrict__ A_imag,
    const float* __restrict__ Dp,
    float* __restrict__ y)
{
    // stride 261: 261 % 32 = 5 (odd vs 32) -> column accesses conflict-light
    __shared__ float pw_re[N2][CH + 5];   // w^j, j in [0,256]
    __shared__ float pw_im[N2][CH + 5];
    __shared__ float u_ch[CH];
    __shared__ float kloc[CH];
    __shared__ float dtAr[N2], dtAi[N2];
    __shared__ float Ck2r[N2], Ck2i[N2];  // 2*Ck folded
    __shared__ float Sr[N2], Si[N2];
    __shared__ float CkSr[N2], CkSi[N2];

    const int tid = threadIdx.x;
    const int h = blockIdx.x & (Hh - 1);
    const int b = blockIdx.x >> 9;

    const float dt = expf(log_dt[h]);

    if (tid < N2) {
        const int n = tid;
        const float lar = log_A_real[h * N2 + n];
        const float Aim = A_imag[h * N2 + n];
        const float Are = -expf(lar);
        const float dar = Are * dt, dai = Aim * dt;
        dtAr[n] = dar; dtAi[n] = dai;
        // (exp(dtA) - 1) / A
        const float ex = expf(dar);
        float sn, cs; sincosf(dai, &sn, &cs);
        const float er = ex * cs - 1.f, ei = ex * sn;
        const float den = Are * Are + Aim * Aim;
        const float qr = (er * Are + ei * Aim) / den;
        const float qi = (ei * Are - er * Aim) / den;
        const float cr = C_re[h * N2 + n], ci = C_im[h * N2 + n];
        Ck2r[n] = 2.f * (cr * qr - ci * qi);
        Ck2i[n] = 2.f * (cr * qi + ci * qr);
        Sr[n] = 0.f; Si[n] = 0.f;
    }
    __syncthreads();

    // pw[n][j] = exp(dtA_n * j), j = 0..256  (8224 entries)
    for (int idx = tid; idx < 257 * N2; idx += 256) {
        const int n = idx & (N2 - 1);
        const int j = idx >> 5;
        const float jf = (float)j;
        const float ex = expf(dtAr[n] * jf);
        float sn, cs; sincosf(dtAi[n] * jf, &sn, &cs);
        pw_re[n][j] = ex * cs;
        pw_im[n][j] = ex * sn;
    }
    __syncthreads();

    // kloc[t] = 2 Re( sum_n Ck_n w_n^t )
    {
        float kv = 0.f;
        #pragma unroll
        for (int n = 0; n < N2; ++n)
            kv += Ck2r[n] * pw_re[n][tid] - Ck2i[n] * pw_im[n][tid];
        kloc[tid] = kv;
    }
    // kloc consumed after the in-loop __syncthreads below.

    const float Dh = Dp[h];
    const float* ub = u + ((size_t)(b * Hh + h)) * Ll;
    float* yb = y + ((size_t)(b * Hh + h)) * Ll;

    for (int c = 0; c < NCH; ++c) {
        // phase 1: snapshot Ck*S, load u chunk
        if (tid < N2) {
            const float sr = Sr[tid], si = Si[tid];
            CkSr[tid] = Ck2r[tid] * sr - Ck2i[tid] * si;
            CkSi[tid] = Ck2r[tid] * si + Ck2i[tid] * sr;
        }
        u_ch[tid] = ub[c * CH + tid];
        __syncthreads();

        // phase 2a: intra-chunk lower-triangular Toeplitz conv
        float acc = 0.f;
        #pragma unroll 4
        for (int s = 0; s <= tid; ++s)
            acc += kloc[tid - s] * u_ch[s];

        // phase 2b: carried-state contribution 2Re(sum_n CkS_n w^{t+1})
        float yst = 0.f;
        #pragma unroll
        for (int n = 0; n < N2; ++n)
            yst += CkSr[n] * pw_re[n][tid + 1] - CkSi[n] * pw_im[n][tid + 1];

        float yv = acc + yst + u_ch[tid] * Dh;
        // exact GELU (erf-based)
        yv = 0.5f * yv * (1.f + erff(yv * 0.70710678118654752f));
        yb[c * CH + tid] = yv;

        // phase 2c: P_n = sum_s w^{255-s} u[s] ; S <- w^C S + P
        const int n = tid >> 3, g = tid & 7;
        float pr = 0.f, pi = 0.f;
        #pragma unroll 8
        for (int k = 0; k < 32; ++k) {
            const int s = g + (k << 3);
            const float uu = u_ch[s];
            pr += pw_re[n][255 - s] * uu;
            pi += pw_im[n][255 - s] * uu;
        }
        pr += __shfl_down(pr, 4, 8);
        pi += __shfl_down(pi, 4, 8);
        pr += __shfl_down(pr, 2, 8);
        pi += __shfl_down(pi, 2, 8);
        pr += __shfl_down(pr, 1, 8);
        pi += __shfl_down(pi, 1, 8);
        if (g == 0) {
            const float wr = pw_re[n][CH], wi = pw_im[n][CH];
            const float sr = Sr[n], si = Si[n];
            Sr[n] = wr * sr - wi * si + pr;
            Si[n] = wr * si + wi * sr + pi;
        }
        __syncthreads();
    }
}

// ---------------- Stage 2: z = W @ y + b, GLU(a, g) fused --------------------
// W: (2H, H) row-major. Columns = (b, l) flattened; tiles 64 rows x 64 cols,
// each workgroup computes BOTH the a-half (rows m) and g-half (rows m+512).
__global__ __launch_bounds__(256, 4) void s4d_stage2(
    const float* __restrict__ y,
    const float* __restrict__ W,
    const float* __restrict__ bias,
    float* __restrict__ out)
{
    __shared__ float WaT[16][68];  // [k][row]
    __shared__ float WgT[16][68];
    __shared__ float Yt[16][68];   // [k][col]

    const int tid = threadIdx.x;
    const int ct = blockIdx.x;            // 0..511 column tiles
    const int mt = blockIdx.y;            // 0..7 row tiles (a-half)
    const int col0 = ct << 6;
    const int b = col0 >> 12;
    const int l0 = col0 & (Ll - 1);
    const int m0 = mt << 6;
    const int tx = tid & 15, ty = tid >> 4;

    float accA[4][4] = {{0.f}}, accG[4][4] = {{0.f}};

    const int kc = tid & 15, r0 = tid >> 4;
    const int cc = tid & 63, kr0 = tid >> 6;

    for (int kk = 0; kk < Hh; kk += 16) {
        #pragma unroll
        for (int q = 0; q < 4; ++q) {
            const int r = r0 + (q << 4);
            WaT[kc][r] = W[(m0 + r) * Hh + kk + kc];
            WgT[kc][r] = W[(m0 + 512 + r) * Hh + kk + kc];
        }
        #pragma unroll
        for (int q = 0; q < 4; ++q) {
            const int kr = kr0 + (q << 2);
            Yt[kr][cc] = y[((size_t)b * Hh + (kk + kr)) * Ll + l0 + cc];
        }
        __syncthreads();

        #pragma unroll
        for (int k = 0; k < 16; ++k) {
            const float4 a4 = *(const float4*)&WaT[k][ty << 2];
            const float4 g4 = *(const float4*)&WgT[k][ty << 2];
            const float4 b4 = *(const float4*)&Yt[k][tx << 2];
            const float av[4] = {a4.x, a4.y, a4.z, a4.w};
            const float gv[4] = {g4.x, g4.y, g4.z, g4.w};
            const float bv[4] = {b4.x, b4.y, b4.z, b4.w};
            #pragma unroll
            for (int j = 0; j < 4; ++j)
                #pragma unroll
                for (int i = 0; i < 4; ++i) {
                    accA[j][i] += av[j] * bv[i];
                    accG[j][i] += gv[j] * bv[i];
                }
        }
        __syncthreads();
    }

    #pragma unroll
    for (int j = 0; j < 4; ++j) {
        const int hrow = m0 + (ty << 2) + j;
        const float ba = bias[hrow], bg = bias[hrow + 512];
        float4 o;
        float av, gv;
        av = accA[j][0] + ba; gv = accG[j][0] + bg; o.x = av / (1.f + expf(-gv));
        av = accA[j][1] + ba; gv = accG[j][1] + bg; o.y = av / (1.f + expf(-gv));
        av = accA[j][2] + ba; gv = accG[j][2] + bg; o.z = av / (1.f + expf(-gv));
        av = accA[j][3] + ba; gv = accG[j][3] + bg; o.w = av / (1.f + expf(-gv));
        *(float4*)&out[((size_t)b * Hh + hrow) * Ll + l0 + (tx << 2)] = o;
    }
}

extern "C" void kernel_launch(void* const* d_in, const int* in_sizes, int n_in,
                              void* d_out, int out_size, void* d_ws, size_t ws_size,
                              hipStream_t stream)
{
    const float* u          = (const float*)d_in[0];
    const float* log_dt     = (const float*)d_in[1];
    const float* C_re       = (const float*)d_in[2];
    const float* C_im       = (const float*)d_in[3];
    const float* log_A_real = (const float*)d_in[4];
    const float* A_imag     = (const float*)d_in[5];
    const float* Dp         = (const float*)d_in[6];
    const float* W          = (const float*)d_in[7];
    const float* bias       = (const float*)d_in[8];
    float* out  = (float*)d_out;
    float* y_ws = (float*)d_ws;   // (B,H,L) fp32 = 64 MiB

    s4d_stage1<<<dim3(Bb * Hh), dim3(256), 0, stream>>>(
        u, log_dt, C_re, C_im, log_A_real, A_imag, Dp, y_ws);
    s4d_stage2<<<dim3(512, 8), dim3(256), 0, stream>>>(
        y_ws, W, bias, out);
}

// Round 2
// 850.641 us; speedup vs baseline: 1.6618x; 1.6618x over previous
//
#include <hip/hip_runtime.h>
#include <math.h>

#define Bb 8
#define Hh 512
#define N2 32
#define Ll 4096
#define CH 256
#define NCH 16

// scratch region in d_out head (overwritten by stage 2 at the end):
#define KG_OFF  0                     // [512][256] k kernel
#define CKR_OFF (512*256)             // [512][32]  2*Ck real
#define CKI_OFF (512*256 + 512*32)    // [512][32]  2*Ck imag

__device__ __forceinline__ float gelu_f(float x) {
    return 0.5f * x * (1.f + erff(x * 0.70710678118654752f));
}

// ---------- K1: per h, build k[h,0..255] and 2*Ck[h,n] -----------------------
__global__ __launch_bounds__(256) void s4d_k1(
    const float* __restrict__ log_dt,
    const float* __restrict__ C_re,  const float* __restrict__ C_im,
    const float* __restrict__ log_A_real, const float* __restrict__ A_imag,
    float* __restrict__ scratch)
{
    __shared__ __align__(16) float wLr[N2][257];   // w^{j+1}, j in [0,256)
    __shared__ __align__(16) float wLi[N2][257];
    __shared__ float Ck2r[N2], Ck2i[N2];

    const int tid = threadIdx.x;
    const int h = blockIdx.x;
    const float dt = expf(log_dt[h]);
    const int n = tid & 31, tq = tid >> 5;

    const float lar = log_A_real[h * N2 + n];
    const float Aim = A_imag[h * N2 + n];
    const float Are = -expf(lar);
    const float dar = Are * dt, dai = Aim * dt;

    float wr, wi;
    { float e = expf(dar); float sn, cs; sincosf(dai, &sn, &cs); wr = e * cs; wi = e * sn; }
    // cur = w^{32*tq+1}
    const float j0 = (float)(32 * tq + 1);
    float cr, ci;
    { float e = expf(dar * j0); float sn, cs; sincosf(dai * j0, &sn, &cs); cr = e * cs; ci = e * sn; }
    #pragma unroll 8
    for (int i = 0; i < 32; ++i) {
        const int j = 32 * tq + i;
        wLr[n][j] = cr; wLi[n][j] = ci;
        const float tr = cr * wr - ci * wi;
        ci = cr * wi + ci * wr; cr = tr;
    }

    if (tid < N2) {
        // (exp(dtA)-1)/A ; note wr,wi == exp(dtA) for this n
        const float er = wr - 1.f, ei = wi;
        const float den = Are * Are + Aim * Aim;
        const float qr = (er * Are + ei * Aim) / den;
        const float qi = (ei * Are - er * Aim) / den;
        const float c_r = C_re[h * N2 + tid], c_i = C_im[h * N2 + tid];
        const float k2r = 2.f * (c_r * qr - c_i * qi);
        const float k2i = 2.f * (c_r * qi + c_i * qr);
        Ck2r[tid] = k2r; Ck2i[tid] = k2i;
        scratch[CKR_OFF + h * 32 + tid] = k2r;
        scratch[CKI_OFF + h * 32 + tid] = k2i;
    }
    __syncthreads();

    // k[t] = sum_n (Ck2r*Re(w^t) - Ck2i*Im(w^t)); w^0 = 1
    {
        const int t = tid;
        float kv = 0.f;
        if (t == 0) {
            #pragma unroll
            for (int m = 0; m < N2; ++m) kv += Ck2r[m];
        } else {
            #pragma unroll
            for (int m = 0; m < N2; ++m)
                kv += Ck2r[m] * wLr[m][t - 1] - Ck2i[m] * wLi[m][t - 1];
        }
        scratch[KG_OFF + h * CH + t] = kv;
    }
}

// ---------- K2: per (b,h), intra-chunk Toeplitz + D*u, write yT --------------
__global__ __launch_bounds__(256) void s4d_k2(
    const float* __restrict__ u, const float* __restrict__ Dp,
    const float* __restrict__ scratch, float* __restrict__ y)
{
    __shared__ __align__(16) float u_ch2[NCH][CH];
    __shared__ __align__(16) float kpad[512];

    const int tid = threadIdx.x;
    const int h = blockIdx.x & (Hh - 1);
    const int b = blockIdx.x >> 9;
    const float* ub = u + (size_t)(b * Hh + h) * Ll;

    #pragma unroll
    for (int q = 0; q < 4; ++q) {
        const int l = q * 1024 + tid * 4;
        const float4 v = *(const float4*)&ub[l];
        *(float4*)&u_ch2[l >> 8][l & 255] = v;
    }
    kpad[tid] = 0.f;
    kpad[256 + tid] = scratch[KG_OFF + h * CH + tid];
    __syncthreads();

    // wave->t-quarter permuted per block to balance triangular work across SIMDs
    const int w = ((tid >> 6) + blockIdx.x) & 3;
    const int lam = tid & 63;
    const int t0 = 64 * w + 4 * (lam & 15);
    const int cg = lam >> 4;

    float acc[4][4] = {{0.f}};
    const int s0max = 64 * w + 60;
    for (int s0 = 0; s0 <= s0max; s0 += 4) {
        const float4 ka = *(const float4*)&kpad[252 + t0 - s0];
        const float4 kb = *(const float4*)&kpad[256 + t0 - s0];
        const float kk[8] = {ka.x, ka.y, ka.z, ka.w, kb.x, kb.y, kb.z, kb.w};
        #pragma unroll
        for (int j = 0; j < 4; ++j) {
            const float4 u4 = *(const float4*)&u_ch2[4 * cg + j][s0];
            #pragma unroll
            for (int dt = 0; dt < 4; ++dt) {
                acc[dt][j] += kk[4 + dt] * u4.x + kk[3 + dt] * u4.y
                            + kk[2 + dt] * u4.z + kk[1 + dt] * u4.w;
            }
        }
    }

    const float Dh = Dp[h];
    float* yb = y + (size_t)(b * Hh + h) * Ll;
    #pragma unroll
    for (int j = 0; j < 4; ++j) {
        const int c = 4 * cg + j;
        const float4 ud = *(const float4*)&u_ch2[c][t0];
        float4 o;
        o.x = acc[0][j] + Dh * ud.x;
        o.y = acc[1][j] + Dh * ud.y;
        o.z = acc[2][j] + Dh * ud.z;
        o.w = acc[3][j] + Dh * ud.w;
        *(float4*)&yb[c * CH + t0] = o;
    }
}

// ---------- K3: per (b,h), P recurrence + scan + state matmul + GELU ---------
#define WST 260   // row stride for wsh (mult of 4 for alignment, %32==4)
__global__ __launch_bounds__(256) void s4d_k3(
    const float* __restrict__ u,
    const float* __restrict__ log_dt,
    const float* __restrict__ log_A_real, const float* __restrict__ A_imag,
    const float* __restrict__ scratch, float* __restrict__ y)
{
    __shared__ __align__(16) float wshr[N2 * WST];  // [n][j] = Re(w^{j+1})
    __shared__ __align__(16) float wshi[N2 * WST];
    __shared__ __align__(16) float Pr[N2][16], Pi[N2][16];
    __shared__ __align__(16) float CkSr[N2][16], CkSi[N2][16];

    const int tid = threadIdx.x;
    const int h = blockIdx.x & (Hh - 1);
    const int b = blockIdx.x >> 9;
    const int n = tid & 31, tq = tid >> 5;

    // rebuild w table (cheap; avoids a 34 MB global table)
    {
        const float dt = expf(log_dt[h]);
        const float Are = -expf(log_A_real[h * N2 + n]);
        const float dar = Are * dt, dai = A_imag[h * N2 + n] * dt;
        float wr, wi;
        { float e = expf(dar); float sn, cs; sincosf(dai, &sn, &cs); wr = e * cs; wi = e * sn; }
        const float j0 = (float)(32 * tq + 1);
        float cr, ci;
        { float e = expf(dar * j0); float sn, cs; sincosf(dai * j0, &sn, &cs); cr = e * cs; ci = e * sn; }
        #pragma unroll 8
        for (int i = 0; i < 32; ++i) {
            const int j = 32 * tq + i;
            wshr[n * WST + j] = cr; wshi[n * WST + j] = ci;
            const float tr = cr * wr - ci * wi;
            ci = cr * wi + ci * wr; cr = tr;
        }
    }
    __syncthreads();

    // P[n][c] = sum_s w^{255-s} u[c*256+s], via ascending-power recurrence
    {
        const int cp = tid >> 5;            // 2 chunks per thread
        const float* ub = u + (size_t)(b * Hh + h) * Ll;
        const float w1r = wshr[n * WST], w1i = wshi[n * WST];
        float cr = 1.f, ci = 0.f;           // w^0
        float p0r = 0.f, p0i = 0.f, p1r = 0.f, p1i = 0.f;
        const float* u0 = ub + (2 * cp) * CH;
        const float* u1 = ub + (2 * cp + 1) * CH;
        #pragma unroll 4
        for (int i = 0; i < CH; ++i) {
            const int s = 255 - i;
            const float a0 = u0[s], a1 = u1[s];
            p0r += cr * a0; p0i += ci * a0;
            p1r += cr * a1; p1i += ci * a1;
            const float tr = cr * w1r - ci * w1i;
            ci = cr * w1i + ci * w1r; cr = tr;
        }
        Pr[n][2 * cp] = p0r;     Pi[n][2 * cp] = p0i;
        Pr[n][2 * cp + 1] = p1r; Pi[n][2 * cp + 1] = p1i;
    }
    __syncthreads();

    if (tid < N2) {
        const float k2r = scratch[CKR_OFF + h * 32 + tid];
        const float k2i = scratch[CKI_OFF + h * 32 + tid];
        const float wCr = wshr[tid * WST + 255], wCi = wshi[tid * WST + 255]; // w^256
        float sr = 0.f, si = 0.f;
        #pragma unroll
        for (int c = 0; c < NCH; ++c) {
            CkSr[tid][c] = k2r * sr - k2i * si;
            CkSi[tid][c] = k2r * si + k2i * sr;
            const float nr = wCr * sr - wCi * si + Pr[tid][c];
            si = wCr * si + wCi * sr + Pi[tid][c];
            sr = nr;
        }
    }
    __syncthreads();

    // y_state[t][c] = sum_n (CkSr*Re(w^{t+1}) - CkSi*Im(w^{t+1})), tiled 4t x 4c
    const int w = tid >> 6, lam = tid & 63;
    const int t0 = 64 * w + 4 * (lam & 15), cg = lam >> 4;
    float acc[4][4] = {{0.f}};
    #pragma unroll 4
    for (int m = 0; m < N2; ++m) {
        const float4 wr4 = *(const float4*)&wshr[m * WST + t0];
        const float4 wi4 = *(const float4*)&wshi[m * WST + t0];
        const float4 sr4 = *(const float4*)&CkSr[m][4 * cg];
        const float4 si4 = *(const float4*)&CkSi[m][4 * cg];
        const float wrA[4] = {wr4.x, wr4.y, wr4.z, wr4.w};
        const float wiA[4] = {wi4.x, wi4.y, wi4.z, wi4.w};
        const float srA[4] = {sr4.x, sr4.y, sr4.z, sr4.w};
        const float siA[4] = {si4.x, si4.y, si4.z, si4.w};
        #pragma unroll
        for (int dt = 0; dt < 4; ++dt)
            #pragma unroll
            for (int j = 0; j < 4; ++j)
                acc[dt][j] += wrA[dt] * srA[j] - wiA[dt] * siA[j];
    }

    float* yb = y + (size_t)(b * Hh + h) * Ll;
    #pragma unroll
    for (int j = 0; j < 4; ++j) {
        const int c = 4 * cg + j;
        float4 v = *(float4*)&yb[c * CH + t0];
        v.x = gelu_f(v.x + acc[0][j]);
        v.y = gelu_f(v.y + acc[1][j]);
        v.z = gelu_f(v.z + acc[2][j]);
        v.w = gelu_f(v.w + acc[3][j]);
        *(float4*)&yb[c * CH + t0] = v;
    }
}

// ---------------- Stage 2: z = W @ y + b, GLU(a, g) fused --------------------
__global__ __launch_bounds__(256, 4) void s4d_stage2(
    const float* __restrict__ y,
    const float* __restrict__ W,
    const float* __restrict__ bias,
    float* __restrict__ out)
{
    __shared__ float WaT[16][68];
    __shared__ float WgT[16][68];
    __shared__ float Yt[16][68];

    const int tid = threadIdx.x;
    const int ct = blockIdx.x;
    const int mt = blockIdx.y;
    const int col0 = ct << 6;
    const int b = col0 >> 12;
    const int l0 = col0 & (Ll - 1);
    const int m0 = mt << 6;
    const int tx = tid & 15, ty = tid >> 4;

    float accA[4][4] = {{0.f}}, accG[4][4] = {{0.f}};

    const int kc = tid & 15, r0 = tid >> 4;
    const int cc = tid & 63, kr0 = tid >> 6;

    for (int kk = 0; kk < Hh; kk += 16) {
        #pragma unroll
        for (int q = 0; q < 4; ++q) {
            const int r = r0 + (q << 4);
            WaT[kc][r] = W[(m0 + r) * Hh + kk + kc];
            WgT[kc][r] = W[(m0 + 512 + r) * Hh + kk + kc];
        }
        #pragma unroll
        for (int q = 0; q < 4; ++q) {
            const int kr = kr0 + (q << 2);
            Yt[kr][cc] = y[((size_t)b * Hh + (kk + kr)) * Ll + l0 + cc];
        }
        __syncthreads();

        #pragma unroll
        for (int k = 0; k < 16; ++k) {
            const float4 a4 = *(const float4*)&WaT[k][ty << 2];
            const float4 g4 = *(const float4*)&WgT[k][ty << 2];
            const float4 b4 = *(const float4*)&Yt[k][tx << 2];
            const float av[4] = {a4.x, a4.y, a4.z, a4.w};
            const float gv[4] = {g4.x, g4.y, g4.z, g4.w};
            const float bv[4] = {b4.x, b4.y, b4.z, b4.w};
            #pragma unroll
            for (int j = 0; j < 4; ++j)
                #pragma unroll
                for (int i = 0; i < 4; ++i) {
                    accA[j][i] += av[j] * bv[i];
                    accG[j][i] += gv[j] * bv[i];
                }
        }
        __syncthreads();
    }

    #pragma unroll
    for (int j = 0; j < 4; ++j) {
        const int hrow = m0 + (ty << 2) + j;
        const float ba = bias[hrow], bg = bias[hrow + 512];
        float4 o;
        float av, gv;
        av = accA[j][0] + ba; gv = accG[j][0] + bg; o.x = av / (1.f + expf(-gv));
        av = accA[j][1] + ba; gv = accG[j][1] + bg; o.y = av / (1.f + expf(-gv));
        av = accA[j][2] + ba; gv = accG[j][2] + bg; o.z = av / (1.f + expf(-gv));
        av = accA[j][3] + ba; gv = accG[j][3] + bg; o.w = av / (1.f + expf(-gv));
        *(float4*)&out[((size_t)b * Hh + hrow) * Ll + l0 + (tx << 2)] = o;
    }
}

extern "C" void kernel_launch(void* const* d_in, const int* in_sizes, int n_in,
                              void* d_out, int out_size, void* d_ws, size_t ws_size,
                              hipStream_t stream)
{
    const float* u          = (const float*)d_in[0];
    const float* log_dt     = (const float*)d_in[1];
    const float* C_re       = (const float*)d_in[2];
    const float* C_im       = (const float*)d_in[3];
    const float* log_A_real = (const float*)d_in[4];
    const float* A_imag     = (const float*)d_in[5];
    const float* Dp         = (const float*)d_in[6];
    const float* W          = (const float*)d_in[7];
    const float* bias       = (const float*)d_in[8];
    float* out     = (float*)d_out;
    float* y_ws    = (float*)d_ws;       // (B,H,L) fp32 = 64 MiB
    float* scratch = (float*)d_out;      // head of d_out; overwritten by stage 2

    s4d_k1<<<dim3(Hh), dim3(256), 0, stream>>>(
        log_dt, C_re, C_im, log_A_real, A_imag, scratch);
    s4d_k2<<<dim3(Bb * Hh), dim3(256), 0, stream>>>(
        u, Dp, scratch, y_ws);
    s4d_k3<<<dim3(Bb * Hh), dim3(256), 0, stream>>>(
        u, log_dt, log_A_real, A_imag, scratch, y_ws);
    s4d_stage2<<<dim3(512, 8), dim3(256), 0, stream>>>(
        y_ws, W, bias, out);
}

// Round 3
// 417.474 us; speedup vs baseline: 3.3860x; 2.0376x over previous
//
#include <hip/hip_runtime.h>
#include <hip/hip_bf16.h>
#include <math.h>

#define Bb 8
#define Hh 512
#define N2 32
#define Ll 4096
#define CH 256
#define NCH 16

// scratch in d_out (floats); y_bf16 occupies d_out float-index [0, 8M)
#define KG_OFF  8388608
#define CKR_OFF (KG_OFF + 131072)
#define CKI_OFF (CKR_OFF + 16384)

typedef short bf16x8 __attribute__((ext_vector_type(8)));
typedef float f32x4  __attribute__((ext_vector_type(4)));

__device__ __forceinline__ float gelu_f(float x) {
    return 0.5f * x * (1.f + erff(x * 0.70710678118654752f));
}
__device__ __forceinline__ unsigned short f2bf(float f) {
    __hip_bfloat16 h = __float2bfloat16(f);
    return *reinterpret_cast<unsigned short*>(&h);
}

// ---------- K1: per h, k[h,0..255], 2*Ck[h,n]; plus W -> bf16 ----------------
__global__ __launch_bounds__(256) void s4d_k1(
    const float* __restrict__ log_dt,
    const float* __restrict__ C_re,  const float* __restrict__ C_im,
    const float* __restrict__ log_A_real, const float* __restrict__ A_imag,
    const float* __restrict__ W,
    float* __restrict__ scratch, unsigned short* __restrict__ Wb)
{
    __shared__ __align__(16) float wLr[N2][257];
    __shared__ __align__(16) float wLi[N2][257];
    __shared__ float Ck2r[N2], Ck2i[N2];

    const int tid = threadIdx.x;
    const int h = blockIdx.x;

    // W fp32 -> bf16 (flat)
    {
        const int i4 = (blockIdx.x * 256 + tid) * 4;
        const float4 wv = *(const float4*)&W[i4];
        unsigned short o[4] = {f2bf(wv.x), f2bf(wv.y), f2bf(wv.z), f2bf(wv.w)};
        *(uint2*)&Wb[i4] = *(uint2*)o;
    }

    const float dt = expf(log_dt[h]);
    const int n = tid & 31, tq = tid >> 5;

    const float lar = log_A_real[h * N2 + n];
    const float Aim = A_imag[h * N2 + n];
    const float Are = -expf(lar);
    const float dar = Are * dt, dai = Aim * dt;

    float wr, wi;
    { float e = expf(dar); float sn, cs; sincosf(dai, &sn, &cs); wr = e * cs; wi = e * sn; }
    const float j0 = (float)(32 * tq + 1);
    float cr, ci;
    { float e = expf(dar * j0); float sn, cs; sincosf(dai * j0, &sn, &cs); cr = e * cs; ci = e * sn; }
    #pragma unroll 8
    for (int i = 0; i < 32; ++i) {
        const int j = 32 * tq + i;
        wLr[n][j] = cr; wLi[n][j] = ci;
        const float tr = cr * wr - ci * wi;
        ci = cr * wi + ci * wr; cr = tr;
    }

    if (tid < N2) {
        const float er = wr - 1.f, ei = wi;
        const float den = Are * Are + Aim * Aim;
        const float qr = (er * Are + ei * Aim) / den;
        const float qi = (ei * Are - er * Aim) / den;
        const float c_r = C_re[h * N2 + tid], c_i = C_im[h * N2 + tid];
        const float k2r = 2.f * (c_r * qr - c_i * qi);
        const float k2i = 2.f * (c_r * qi + c_i * qr);
        Ck2r[tid] = k2r; Ck2i[tid] = k2i;
        scratch[CKR_OFF + h * 32 + tid] = k2r;
        scratch[CKI_OFF + h * 32 + tid] = k2i;
    }
    __syncthreads();

    {
        const int t = tid;
        float kv = 0.f;
        if (t == 0) {
            #pragma unroll
            for (int m = 0; m < N2; ++m) kv += Ck2r[m];
        } else {
            #pragma unroll
            for (int m = 0; m < N2; ++m)
                kv += Ck2r[m] * wLr[m][t - 1] - Ck2i[m] * wLi[m][t - 1];
        }
        scratch[KG_OFF + h * CH + t] = kv;
    }
}

// ---------- K23: fused Toeplitz + P recurrence + scan + state + GELU ---------
#define WSTRIDE 260
__global__ __launch_bounds__(256) void s4d_k23(
    const float* __restrict__ u,
    const float* __restrict__ log_dt,
    const float* __restrict__ log_A_real, const float* __restrict__ A_imag,
    const float* __restrict__ Dp,
    const float* scratch, unsigned short* y_bf)
{
    __shared__ __align__(16) float u_ch[NCH][CH];     // 16 KB
    __shared__ __align__(16) float kpad[512];         // 2 KB
    __shared__ __align__(16) unsigned int wtab[N2 * WSTRIDE]; // packed bf16 re|im<<16
    __shared__ float w256r[N2], w256i[N2];
    __shared__ __align__(16) float Pr[N2][NCH], Pi[N2][NCH];
    __shared__ __align__(16) float CkSr[N2][NCH], CkSi[N2][NCH];

    const int tid = threadIdx.x;
    const int h = blockIdx.x & (Hh - 1);
    const int b = blockIdx.x >> 9;
    const int n = tid & 31, tq = tid >> 5;
    const float* ub = u + (size_t)(b * Hh + h) * Ll;

    // load u row + k
    #pragma unroll
    for (int q = 0; q < 4; ++q) {
        const int l = q * 1024 + tid * 4;
        const float4 v = *(const float4*)&ub[l];
        *(float4*)&u_ch[l >> 8][l & 255] = v;
    }
    kpad[tid] = 0.f;
    kpad[256 + tid] = scratch[KG_OFF + h * CH + tid];

    // build packed w table; keep w^1 in regs for P recurrence
    float w1r, w1i;
    {
        const float dt = expf(log_dt[h]);
        const float Are = -expf(log_A_real[h * N2 + n]);
        const float dar = Are * dt, dai = A_imag[h * N2 + n] * dt;
        { float e = expf(dar); float sn, cs; sincosf(dai, &sn, &cs); w1r = e * cs; w1i = e * sn; }
        const float j0 = (float)(32 * tq + 1);
        float cr, ci;
        { float e = expf(dar * j0); float sn, cs; sincosf(dai * j0, &sn, &cs); cr = e * cs; ci = e * sn; }
        #pragma unroll 8
        for (int i = 0; i < 32; ++i) {
            const int j = 32 * tq + i;
            wtab[n * WSTRIDE + j] =
                (unsigned int)f2bf(cr) | ((unsigned int)f2bf(ci) << 16);
            if (j == 255) { w256r[n] = cr; w256i[n] = ci; }
            const float tr = cr * w1r - ci * w1i;
            ci = cr * w1i + ci * w1r; cr = tr;
        }
    }
    __syncthreads();

    // Toeplitz, wave-permuted for SIMD balance
    const int wperm = ((tid >> 6) + blockIdx.x) & 3;
    const int lam = tid & 63;
    const int t0 = 64 * wperm + 4 * (lam & 15);
    const int cg = lam >> 4;

    float acc[4][4] = {{0.f}};
    const int s0max = 64 * wperm + 60;
    for (int s0 = 0; s0 <= s0max; s0 += 4) {
        const float4 ka = *(const float4*)&kpad[252 + t0 - s0];
        const float4 kb = *(const float4*)&kpad[256 + t0 - s0];
        const float kk[8] = {ka.x, ka.y, ka.z, ka.w, kb.x, kb.y, kb.z, kb.w};
        #pragma unroll
        for (int j = 0; j < 4; ++j) {
            const float4 u4 = *(const float4*)&u_ch[4 * cg + j][s0];
            #pragma unroll
            for (int d = 0; d < 4; ++d) {
                acc[d][j] += kk[4 + d] * u4.x + kk[3 + d] * u4.y
                           + kk[2 + d] * u4.z + kk[1 + d] * u4.w;
            }
        }
    }

    // P recurrence from LDS (broadcast reads)
    {
        const int cp = tid >> 5;
        float cr = 1.f, ci = 0.f;
        float p0r = 0.f, p0i = 0.f, p1r = 0.f, p1i = 0.f;
        #pragma unroll 4
        for (int i = 0; i < CH; ++i) {
            const int s = 255 - i;
            const float a0 = u_ch[2 * cp][s], a1 = u_ch[2 * cp + 1][s];
            p0r += cr * a0; p0i += ci * a0;
            p1r += cr * a1; p1i += ci * a1;
            const float tr = cr * w1r - ci * w1i;
            ci = cr * w1i + ci * w1r; cr = tr;
        }
        Pr[n][2 * cp] = p0r;     Pi[n][2 * cp] = p0i;
        Pr[n][2 * cp + 1] = p1r; Pi[n][2 * cp + 1] = p1i;
    }
    __syncthreads();

    if (tid < N2) {
        const float k2r = scratch[CKR_OFF + h * 32 + tid];
        const float k2i = scratch[CKI_OFF + h * 32 + tid];
        const float wCr = w256r[tid], wCi = w256i[tid];
        float sr = 0.f, si = 0.f;
        #pragma unroll
        for (int c = 0; c < NCH; ++c) {
            CkSr[tid][c] = k2r * sr - k2i * si;
            CkSi[tid][c] = k2r * si + k2i * sr;
            const float nr = wCr * sr - wCi * si + Pr[tid][c];
            si = wCr * si + wCi * sr + Pi[tid][c];
            sr = nr;
        }
    }
    __syncthreads();

    // state matmul from packed bf16 table
    float accs[4][4] = {{0.f}};
    #pragma unroll 4
    for (int m = 0; m < N2; ++m) {
        const uint4 wp = *(const uint4*)&wtab[m * WSTRIDE + t0];
        const unsigned int pw[4] = {wp.x, wp.y, wp.z, wp.w};
        float wrA[4], wiA[4];
        #pragma unroll
        for (int d = 0; d < 4; ++d) {
            wrA[d] = __uint_as_float(pw[d] << 16);
            wiA[d] = __uint_as_float(pw[d] & 0xFFFF0000u);
        }
        const float4 sr4 = *(const float4*)&CkSr[m][4 * cg];
        const float4 si4 = *(const float4*)&CkSi[m][4 * cg];
        const float srA[4] = {sr4.x, sr4.y, sr4.z, sr4.w};
        const float siA[4] = {si4.x, si4.y, si4.z, si4.w};
        #pragma unroll
        for (int d = 0; d < 4; ++d)
            #pragma unroll
            for (int j = 0; j < 4; ++j)
                accs[d][j] += wrA[d] * srA[j] - wiA[d] * siA[j];
    }

    // epilogue: +D*u, GELU, bf16 store
    const float Dh = Dp[h];
    unsigned short* yo = y_bf + (size_t)(b * Hh + h) * Ll;
    #pragma unroll
    for (int j = 0; j < 4; ++j) {
        const int c = 4 * cg + j;
        const float4 ud = *(const float4*)&u_ch[c][t0];
        const float uu[4] = {ud.x, ud.y, ud.z, ud.w};
        unsigned short o[4];
        #pragma unroll
        for (int d = 0; d < 4; ++d) {
            const float yv = acc[d][j] + accs[d][j] + Dh * uu[d];
            o[d] = f2bf(gelu_f(yv));
        }
        *(uint2*)&yo[c * CH + t0] = *(uint2*)o;
    }
}

// ---------- T: y_bf (b,k,l) -> y_T (b,l,k), swizzled LDS transpose -----------
__global__ __launch_bounds__(256) void s4d_T(
    const unsigned short* y_bf, unsigned short* __restrict__ y_T)
{
    __shared__ unsigned short T[64][72];
    const int tid = threadIdx.x;
    const int b  = blockIdx.x >> 9;
    const int k0 = ((blockIdx.x >> 6) & 7) << 6;
    const int l0 = (blockIdx.x & 63) << 6;

    #pragma unroll
    for (int q = 0; q < 2; ++q) {
        const int idx = tid + 256 * q;
        const int kk = idx >> 3, lg = idx & 7;
        const uint4 v = *(const uint4*)&y_bf[((size_t)(b * Hh + k0 + kk)) * Ll + l0 + 8 * lg];
        const int gp = lg ^ ((kk >> 3) & 7);
        *(uint4*)&T[kk][8 * gp] = v;
    }
    __syncthreads();
    #pragma unroll
    for (int q = 0; q < 2; ++q) {
        const int idx = tid + 256 * q;
        const int ll = idx >> 3, kg = idx & 7;
        unsigned short o[8];
        #pragma unroll
        for (int j = 0; j < 8; ++j) {
            const int kr = 8 * kg + j;
            const int gp = (ll >> 3) ^ kg;
            o[j] = T[kr][8 * gp + (ll & 7)];
        }
        *(uint4*)&y_T[((size_t)(b * Ll + l0 + ll)) * Hh + k0 + 8 * kg] = *(uint4*)o;
    }
}

// ---------- Stage 2: MFMA GEMM + GLU ----------------------------------------
__global__ __launch_bounds__(256, 4) void s4d_s2(
    const unsigned short* __restrict__ yT,
    const unsigned short* __restrict__ Wb,
    const float* __restrict__ bias,
    float* __restrict__ out)
{
    __shared__ unsigned short Wlds[128][72];  // rows 0..63 a, 64..127 g
    __shared__ unsigned short Ylds[128][72];  // rows = l

    const int tid = threadIdx.x;
    const int ct = blockIdx.x;               // 256 col tiles
    const int mt = blockIdx.y;               // 8 row tiles
    const int b  = ct >> 5;
    const int l0 = (ct & 31) << 7;
    const int m0 = mt << 6;

    const int wv = tid >> 6, ln = tid & 63;
    const int mrow = 16 * wv + (ln & 15);
    const int kq = (ln >> 4) << 3;

    f32x4 accA[8], accG[8];
    #pragma unroll
    for (int cf = 0; cf < 8; ++cf)
        #pragma unroll
        for (int e = 0; e < 4; ++e) { accA[cf][e] = 0.f; accG[cf][e] = 0.f; }

    for (int kk = 0; kk < Hh; kk += 64) {
        #pragma unroll
        for (int q = 0; q < 4; ++q) {
            const int idx = tid + 256 * q;
            const int r = idx >> 3, kg = idx & 7;
            const int grow = m0 + r + ((r >> 6) * 448);
            const uint4 wvv = *(const uint4*)&Wb[grow * Hh + kk + 8 * kg];
            *(uint4*)&Wlds[r][8 * kg] = wvv;
            const uint4 yvv = *(const uint4*)&yT[((size_t)(b * Ll + l0 + r)) * Hh + kk + 8 * kg];
            *(uint4*)&Ylds[r][8 * kg] = yvv;
        }
        __syncthreads();

        #pragma unroll
        for (int ks = 0; ks < 64; ks += 32) {
            const bf16x8 af = *(const bf16x8*)&Wlds[mrow][ks + kq];
            const bf16x8 gf = *(const bf16x8*)&Wlds[64 + mrow][ks + kq];
            #pragma unroll
            for (int cf = 0; cf < 8; ++cf) {
                const bf16x8 bfr = *(const bf16x8*)&Ylds[cf * 16 + (ln & 15)][ks + kq];
                accA[cf] = __builtin_amdgcn_mfma_f32_16x16x32_bf16(af, bfr, accA[cf], 0, 0, 0);
                accG[cf] = __builtin_amdgcn_mfma_f32_16x16x32_bf16(gf, bfr, accG[cf], 0, 0, 0);
            }
        }
        __syncthreads();
    }

    const int mb = m0 + 16 * wv + ((ln >> 4) << 2);
    float bA[4], bG[4];
    #pragma unroll
    for (int r = 0; r < 4; ++r) { bA[r] = bias[mb + r]; bG[r] = bias[mb + r + 512]; }

    #pragma unroll
    for (int cf = 0; cf < 8; ++cf) {
        const int l = l0 + cf * 16 + (ln & 15);
        #pragma unroll
        for (int r = 0; r < 4; ++r) {
            const float a = accA[cf][r] + bA[r];
            const float g = accG[cf][r] + bG[r];
            out[((size_t)(b * Hh + mb + r)) * Ll + l] = a / (1.f + expf(-g));
        }
    }
}

extern "C" void kernel_launch(void* const* d_in, const int* in_sizes, int n_in,
                              void* d_out, int out_size, void* d_ws, size_t ws_size,
                              hipStream_t stream)
{
    const float* u          = (const float*)d_in[0];
    const float* log_dt     = (const float*)d_in[1];
    const float* C_re       = (const float*)d_in[2];
    const float* C_im       = (const float*)d_in[3];
    const float* log_A_real = (const float*)d_in[4];
    const float* A_imag     = (const float*)d_in[5];
    const float* Dp         = (const float*)d_in[6];
    const float* W          = (const float*)d_in[7];
    const float* bias       = (const float*)d_in[8];

    float* out = (float*)d_out;
    float* scratch = (float*)d_out;                         // floats [8M, ...)
    unsigned short* y_bf = (unsigned short*)d_out;          // bf16 [0, 32MiB)
    unsigned short* y_T  = (unsigned short*)d_ws;           // 32 MiB
    unsigned short* Wb   = (unsigned short*)((char*)d_ws + (32u << 20)); // 1 MiB

    s4d_k1<<<dim3(Hh), dim3(256), 0, stream>>>(
        log_dt, C_re, C_im, log_A_real, A_imag, W, scratch, Wb);
    s4d_k23<<<dim3(Bb * Hh), dim3(256), 0, stream>>>(
        u, log_dt, log_A_real, A_imag, Dp, scratch, y_bf);
    s4d_T<<<dim3(Bb * Hh), dim3(256), 0, stream>>>(y_bf, y_T);
    s4d_s2<<<dim3(256, 8), dim3(256), 0, stream>>>(y_T, Wb, bias, out);
}

// Round 5
// 313.802 us; speedup vs baseline: 4.5046x; 1.3304x over previous
//
#include <hip/hip_runtime.h>
#include <hip/hip_bf16.h>
#include <math.h>

#define Bb 8
#define Hh 512
#define N2 32
#define Ll 4096
#define CH 256
#define NCH 16

// scratch in d_out (floats); y_bf16 occupies d_out bytes [0, 32MiB)
#define KG_OFF  8388608
#define CKR_OFF (KG_OFF + 131072)
#define CKI_OFF (CKR_OFF + 16384)

typedef short bf16x8 __attribute__((ext_vector_type(8)));
typedef float f32x4  __attribute__((ext_vector_type(4)));

__device__ __forceinline__ float gelu_f(float x) {
    return 0.5f * x * (1.f + erff(x * 0.70710678118654752f));
}
__device__ __forceinline__ unsigned short f2bf(float f) {
    __hip_bfloat16 h = __float2bfloat16(f);
    return *reinterpret_cast<unsigned short*>(&h);
}
__device__ __forceinline__ float bf2f(unsigned short s) {
    return __uint_as_float(((unsigned int)s) << 16);
}

// ---------- K1: per h, k[h,0..255], 2*Ck[h,n]; plus W -> bf16 ----------------
__global__ __launch_bounds__(256) void s4d_k1(
    const float* __restrict__ log_dt,
    const float* __restrict__ C_re,  const float* __restrict__ C_im,
    const float* __restrict__ log_A_real, const float* __restrict__ A_imag,
    const float* __restrict__ W,
    float* __restrict__ scratch, unsigned short* __restrict__ Wb)
{
    __shared__ __align__(16) float wLr[N2][257];
    __shared__ __align__(16) float wLi[N2][257];
    __shared__ float Ck2r[N2], Ck2i[N2];

    const int tid = threadIdx.x;
    const int h = blockIdx.x;

    // W fp32 -> bf16 (flat)
    {
        const int i4 = (blockIdx.x * 256 + tid) * 4;
        const float4 wv = *(const float4*)&W[i4];
        unsigned short o[4] = {f2bf(wv.x), f2bf(wv.y), f2bf(wv.z), f2bf(wv.w)};
        *(uint2*)&Wb[i4] = *(uint2*)o;
    }

    const float dt = expf(log_dt[h]);
    const int n = tid & 31, tq = tid >> 5;

    const float lar = log_A_real[h * N2 + n];
    const float Aim = A_imag[h * N2 + n];
    const float Are = -expf(lar);
    const float dar = Are * dt, dai = Aim * dt;

    float wr, wi;
    { float e = expf(dar); float sn, cs; sincosf(dai, &sn, &cs); wr = e * cs; wi = e * sn; }
    const float j0 = (float)(32 * tq + 1);
    float cr, ci;
    { float e = expf(dar * j0); float sn, cs; sincosf(dai * j0, &sn, &cs); cr = e * cs; ci = e * sn; }
    #pragma unroll 8
    for (int i = 0; i < 32; ++i) {
        const int j = 32 * tq + i;
        wLr[n][j] = cr; wLi[n][j] = ci;
        const float tr = cr * wr - ci * wi;
        ci = cr * wi + ci * wr; cr = tr;
    }

    if (tid < N2) {
        const float er = wr - 1.f, ei = wi;
        const float den = Are * Are + Aim * Aim;
        const float qr = (er * Are + ei * Aim) / den;
        const float qi = (ei * Are - er * Aim) / den;
        const float c_r = C_re[h * N2 + tid], c_i = C_im[h * N2 + tid];
        const float k2r = 2.f * (c_r * qr - c_i * qi);
        const float k2i = 2.f * (c_r * qi + c_i * qr);
        Ck2r[tid] = k2r; Ck2i[tid] = k2i;
        scratch[CKR_OFF + h * 32 + tid] = k2r;
        scratch[CKI_OFF + h * 32 + tid] = k2i;
    }
    __syncthreads();

    {
        const int t = tid;
        float kv = 0.f;
        if (t == 0) {
            #pragma unroll
            for (int m = 0; m < N2; ++m) kv += Ck2r[m];
        } else {
            #pragma unroll
            for (int m = 0; m < N2; ++m)
                kv += Ck2r[m] * wLr[m][t - 1] - Ck2i[m] * wLi[m][t - 1];
        }
        scratch[KG_OFF + h * CH + t] = kv;
    }
}

// ---------- K23: MFMA-ized Toeplitz + P + scan + state + GELU ----------------
// All matmuls in D^T[c][t] orientation: A-operand rows = chunk c, so
// Toeplitz/state accumulators share one register layout.
// P-matmul uses bf16 w; a fp32 delta-correction for j<128 restores precision.
__global__ __launch_bounds__(256, 2) void s4d_k23(
    const float* __restrict__ u,
    const float* __restrict__ log_dt,
    const float* __restrict__ log_A_real, const float* __restrict__ A_imag,
    const float* __restrict__ Dp,
    const float* scratch, unsigned short* y_bf)
{
    __shared__ __align__(16) unsigned short uhi[16 * 264];   // u reversed, bf16 hi
    __shared__ __align__(16) unsigned short ulo[16 * 264];   // residual
    __shared__ __align__(16) unsigned short khi[8 * 520];    // karr2 shifted copies
    __shared__ __align__(16) unsigned short klo[8 * 520];
    __shared__ __align__(16) unsigned short Wn[64 * 264];    // w^j, n-major, bf16
    __shared__ __align__(16) float Plds[64 * 20];
    __shared__ __align__(16) unsigned short CkAhi[16 * 72];  // [c][2n] CkS split
    __shared__ __align__(16) unsigned short CkAlo[16 * 72];
    __shared__ float w256r[N2], w256i[N2];

    const int tid = threadIdx.x;
    const int h = blockIdx.x & (Hh - 1);
    const int b = blockIdx.x >> 9;
    const int wv = tid >> 6;
    const int lane = tid & 63;
    const int l15 = lane & 15;
    const int quad = lane >> 4;

    // per-thread n-channel params (n = tid&31), used by Wn build AND P-correction
    const int nch = tid & 31;
    const float dt_h = expf(log_dt[h]);
    const float Are_n = -expf(log_A_real[h * N2 + nch]);
    const float dar = Are_n * dt_h, dai = A_imag[h * N2 + nch] * dt_h;
    float w1r, w1i;
    { float e = expf(dar); float sn, cs; sincosf(dai, &sn, &cs); w1r = e * cs; w1i = e * sn; }

    // ---- phase A1: zero karr, u->reversed splits, Wn build ----
    {
        unsigned int* z1 = (unsigned int*)khi;
        unsigned int* z2 = (unsigned int*)klo;
        for (int i = tid; i < 2080; i += 256) { z1[i] = 0; z2[i] = 0; }
    }
    const float* ub = u + (size_t)(b * Hh + h) * Ll;
    #pragma unroll
    for (int q = 0; q < 4; ++q) {
        const int l = q * 1024 + tid * 4;
        const float4 v = *(const float4*)&ub[l];
        const int c = l >> 8, s = l & 255;
        const unsigned short h3 = f2bf(v.w), h2 = f2bf(v.z), h1 = f2bf(v.y), h0 = f2bf(v.x);
        // u_rev[c][252-s .. 255-s] = (u[s+3], u[s+2], u[s+1], u[s])
        uint2 dh;
        dh.x = (unsigned int)h3 | ((unsigned int)h2 << 16);
        dh.y = (unsigned int)h1 | ((unsigned int)h0 << 16);
        *(uint2*)&uhi[c * 264 + (252 - s)] = dh;
        uint2 dl;
        dl.x = (unsigned int)f2bf(v.w - bf2f(h3)) | ((unsigned int)f2bf(v.z - bf2f(h2)) << 16);
        dl.y = (unsigned int)f2bf(v.y - bf2f(h1)) | ((unsigned int)f2bf(v.x - bf2f(h0)) << 16);
        *(uint2*)&ulo[c * 264 + (252 - s)] = dl;
    }
    // own k value for later scatter
    const float kval = scratch[KG_OFF + h * CH + tid];
    const unsigned short k_hi = f2bf(kval);
    const unsigned short k_lo = f2bf(kval - bf2f(k_hi));

    // Wn: thread (n, seg) generates w^j for j in [32seg, 32seg+32)
    {
        const int seg = tid >> 5;
        float cr, ci;
        if (seg == 0) { cr = 1.f; ci = 0.f; }
        else {
            const float jf = (float)(32 * seg);
            float e = expf(dar * jf); float sn, cs; sincosf(dai * jf, &sn, &cs);
            cr = e * cs; ci = e * sn;
        }
        unsigned short prevr = 0, previ = 0;
        #pragma unroll 8
        for (int i = 0; i < 32; ++i) {
            const unsigned short hr = f2bf(cr), hi2 = f2bf(ci);
            if (i & 1) {
                const int j = 32 * seg + i - 1;
                *(unsigned int*)&Wn[(2 * nch) * 264 + j] =
                    (unsigned int)prevr | ((unsigned int)hr << 16);
                *(unsigned int*)&Wn[(2 * nch + 1) * 264 + j] =
                    (unsigned int)previ | ((unsigned int)hi2 << 16);
            } else { prevr = hr; previ = hi2; }
            const float tr = cr * w1r - ci * w1i;
            ci = cr * w1i + ci * w1r; cr = tr;
        }
        if (seg == 7) {   // cr,ci == w^256
            Wn[(2 * nch) * 264 + 256] = f2bf(cr);
            Wn[(2 * nch + 1) * 264 + 256] = f2bf(ci);
            w256r[nch] = cr; w256i[nch] = ci;
        }
    }
    __syncthreads();

    // ---- phase A2: scatter k into 8 shifted copies; P-matmul ----
    #pragma unroll
    for (int r = 0; r < 8; ++r) {
        const int x = tid + 255 - r;
        khi[r * 520 + x] = k_hi;
        klo[r * 520 + x] = k_lo;
    }
    {   // P^T[c][2n]: wave wv owns 2n-cols [16wv, 16wv+16)
        f32x4 accP = {0.f, 0.f, 0.f, 0.f};
        const int wrow = (16 * wv + l15) * 264;
        #pragma unroll
        for (int j0 = 0; j0 < 256; j0 += 32) {
            const bf16x8 ah = *(const bf16x8*)&uhi[l15 * 264 + j0 + 8 * quad];
            const bf16x8 al = *(const bf16x8*)&ulo[l15 * 264 + j0 + 8 * quad];
            const bf16x8 wf = *(const bf16x8*)&Wn[wrow + j0 + 8 * quad];
            accP = __builtin_amdgcn_mfma_f32_16x16x32_bf16(ah, wf, accP, 0, 0, 0);
            accP = __builtin_amdgcn_mfma_f32_16x16x32_bf16(al, wf, accP, 0, 0, 0);
        }
        *(f32x4*)&Plds[(16 * wv + l15) * 20 + 4 * quad] = accP;
    }
    __syncthreads();

    // ---- P fp32 delta-correction for j in [0,128):
    // Plds[2n][c] += sum_j (w^j - bf16(w^j)) * u_rev[c][j]
    // Recurrence reseeded every 32 steps exactly like the Wn build, so
    // f2bf(w_local) reproduces the table bits bit-exactly.
    {
        const int cp = tid >> 5;                 // this thread: n=nch, chunks 2cp,2cp+1
        const float* u0p = ub + (2 * cp) * CH;
        const float* u1p = ub + (2 * cp + 1) * CH;
        float dp0r = 0.f, dp0i = 0.f, dp1r = 0.f, dp1i = 0.f;
        #pragma unroll
        for (int seg = 0; seg < 4; ++seg) {
            float cr, ci;
            if (seg == 0) { cr = 1.f; ci = 0.f; }
            else {
                const float jf = (float)(32 * seg);
                float e = expf(dar * jf); float sn, cs; sincosf(dai * jf, &sn, &cs);
                cr = e * cs; ci = e * sn;
            }
            #pragma unroll 4
            for (int i = 0; i < 32; ++i) {
                const int j = 32 * seg + i;
                const float dr = cr - bf2f(f2bf(cr));
                const float di = ci - bf2f(f2bf(ci));
                const float a0 = u0p[255 - j];
                const float a1 = u1p[255 - j];
                dp0r += dr * a0; dp0i += di * a0;
                dp1r += dr * a1; dp1i += di * a1;
                const float tr = cr * w1r - ci * w1i;
                ci = cr * w1i + ci * w1r; cr = tr;
            }
        }
        Plds[(2 * nch) * 20 + 2 * cp]     += dp0r;
        Plds[(2 * nch + 1) * 20 + 2 * cp] += dp0i;
        Plds[(2 * nch) * 20 + 2 * cp + 1]     += dp1r;
        Plds[(2 * nch + 1) * 20 + 2 * cp + 1] += dp1i;
    }
    __syncthreads();

    // ---- scan (wave0 lanes 0..31) runs concurrent with Toeplitz ----
    if (tid < 32) {
        const int n = tid;
        const float k2r = scratch[CKR_OFF + h * 32 + n];
        const float k2i = scratch[CKI_OFF + h * 32 + n];
        const float wCr = w256r[n], wCi = w256i[n];
        float sr = 0.f, si = 0.f;
        #pragma unroll
        for (int c = 0; c < NCH; ++c) {
            const float vr = k2r * sr - k2i * si;       // A[c][2n]   =  Re(CkS)
            const float vi = -(k2r * si + k2i * sr);    // A[c][2n+1] = -Im(CkS)
            const unsigned short vrh = f2bf(vr), vih = f2bf(vi);
            *(unsigned int*)&CkAhi[c * 72 + 2 * n] =
                (unsigned int)vrh | ((unsigned int)vih << 16);
            *(unsigned int*)&CkAlo[c * 72 + 2 * n] =
                (unsigned int)f2bf(vr - bf2f(vrh)) |
                ((unsigned int)f2bf(vi - bf2f(vih)) << 16);
            const float pr = Plds[(2 * n) * 20 + c], pi = Plds[(2 * n + 1) * 20 + c];
            const float nr = wCr * sr - wCi * si + pr;
            si = wCr * si + wCi * sr + pi;
            sr = nr;
        }
    }

    // ---- Toeplitz: y^T[c][t] += sum_j u_rev[c][j] * karr2[t+j] ----
    f32x4 acc[4];
    #pragma unroll
    for (int i = 0; i < 4; ++i) acc[i] = (f32x4){0.f, 0.f, 0.f, 0.f};
    {
        const int r = lane & 7;
        const int roff = r * 520;
        const int half = ((lane >> 3) & 1) * 8;
        #pragma unroll
        for (int i = 0; i < 4; ++i) {
            const int nt = wv + 4 * i;
            const int jstart = (240 - 16 * nt) & ~31;
            for (int j0 = jstart; j0 < 256; j0 += 32) {
                const bf16x8 ah = *(const bf16x8*)&uhi[l15 * 264 + j0 + 8 * quad];
                const bf16x8 al = *(const bf16x8*)&ulo[l15 * 264 + j0 + 8 * quad];
                const int base = 16 * nt + j0 + 8 * quad + half;
                const bf16x8 bh = *(const bf16x8*)&khi[roff + base];
                const bf16x8 bl = *(const bf16x8*)&klo[roff + base];
                acc[i] = __builtin_amdgcn_mfma_f32_16x16x32_bf16(ah, bh, acc[i], 0, 0, 0);
                acc[i] = __builtin_amdgcn_mfma_f32_16x16x32_bf16(ah, bl, acc[i], 0, 0, 0);
                acc[i] = __builtin_amdgcn_mfma_f32_16x16x32_bf16(al, bh, acc[i], 0, 0, 0);
            }
        }
    }
    __syncthreads();

    // ---- state matmul: acc[c][t] += sum_{2n} CkA[c][2n] * Wn[2n][t+1] ----
    #pragma unroll
    for (int ks = 0; ks < 64; ks += 32) {
        const bf16x8 ah = *(const bf16x8*)&CkAhi[l15 * 72 + ks + 8 * quad];
        const bf16x8 al = *(const bf16x8*)&CkAlo[l15 * 72 + ks + 8 * quad];
        const int kbase = ks + 8 * quad;
        #pragma unroll
        for (int i = 0; i < 4; ++i) {
            const int tcol = 16 * (wv + 4 * i) + l15 + 1;
            bf16x8 bfr;
            #pragma unroll
            for (int m = 0; m < 8; ++m)
                bfr[m] = (short)Wn[(kbase + m) * 264 + tcol];
            acc[i] = __builtin_amdgcn_mfma_f32_16x16x32_bf16(ah, bfr, acc[i], 0, 0, 0);
            acc[i] = __builtin_amdgcn_mfma_f32_16x16x32_bf16(al, bfr, acc[i], 0, 0, 0);
        }
    }

    // ---- epilogue: +D*u, GELU, bf16 store ----
    const float Dh = Dp[h];
    unsigned short* yo = y_bf + (size_t)(b * Hh + h) * Ll;
    #pragma unroll
    for (int i = 0; i < 4; ++i) {
        const int t = 16 * (wv + 4 * i) + l15;
        const int jrev = 255 - t;
        #pragma unroll
        for (int rr = 0; rr < 4; ++rr) {
            const int c = 4 * quad + rr;
            const float uu = bf2f(uhi[c * 264 + jrev]) + bf2f(ulo[c * 264 + jrev]);
            const float yv = acc[i][rr] + Dh * uu;
            yo[c * 256 + t] = f2bf(gelu_f(yv));
        }
    }
}

// ---------- T: y_bf (b,k,l) -> y_T (b,l,k), swizzled LDS transpose -----------
__global__ __launch_bounds__(256) void s4d_T(
    const unsigned short* y_bf, unsigned short* __restrict__ y_T)
{
    __shared__ unsigned short T[64][72];
    const int tid = threadIdx.x;
    const int b  = blockIdx.x >> 9;
    const int k0 = ((blockIdx.x >> 6) & 7) << 6;
    const int l0 = (blockIdx.x & 63) << 6;

    #pragma unroll
    for (int q = 0; q < 2; ++q) {
        const int idx = tid + 256 * q;
        const int kk = idx >> 3, lg = idx & 7;
        const uint4 v = *(const uint4*)&y_bf[((size_t)(b * Hh + k0 + kk)) * Ll + l0 + 8 * lg];
        const int gp = lg ^ ((kk >> 3) & 7);
        *(uint4*)&T[kk][8 * gp] = v;
    }
    __syncthreads();
    #pragma unroll
    for (int q = 0; q < 2; ++q) {
        const int idx = tid + 256 * q;
        const int ll = idx >> 3, kg = idx & 7;
        unsigned short o[8];
        #pragma unroll
        for (int j = 0; j < 8; ++j) {
            const int kr = 8 * kg + j;
            const int gp = (ll >> 3) ^ kg;
            o[j] = T[kr][8 * gp + (ll & 7)];
        }
        *(uint4*)&y_T[((size_t)(b * Ll + l0 + ll)) * Hh + k0 + 8 * kg] = *(uint4*)o;
    }
}

// ---------- Stage 2: 128x128 MFMA GEMM + GLU --------------------------------
__global__ __launch_bounds__(256, 2) void s4d_s2(
    const unsigned short* __restrict__ yT,
    const unsigned short* __restrict__ Wb,
    const float* __restrict__ bias,
    float* __restrict__ out)
{
    __shared__ __align__(16) unsigned short Wlds[128 * 72];  // rows 0..63 a, 64..127 g
    __shared__ __align__(16) unsigned short Ylds[128 * 72];  // rows = l

    const int tid = threadIdx.x;
    const int ct = blockIdx.x;           // 0..255
    const int mt = blockIdx.y;           // 0..7
    const int b  = ct >> 5;
    const int l0 = (ct & 31) << 7;
    const int m0 = mt << 6;

    const int wv = tid >> 6, lane = tid & 63;
    const int l15 = lane & 15, quad = lane >> 4;

    f32x4 accA[8], accG[8];
    #pragma unroll
    for (int j = 0; j < 8; ++j) {
        accA[j] = (f32x4){0.f, 0.f, 0.f, 0.f};
        accG[j] = (f32x4){0.f, 0.f, 0.f, 0.f};
    }

    for (int kk = 0; kk < Hh; kk += 64) {
        #pragma unroll
        for (int q = 0; q < 4; ++q) {
            const int idx = tid + 256 * q;
            const int rr = idx >> 3, kg = idx & 7;
            const int grow = m0 + rr + ((rr >> 6) * 448);
            *(uint4*)&Wlds[rr * 72 + 8 * kg] = *(const uint4*)&Wb[grow * Hh + kk + 8 * kg];
            *(uint4*)&Ylds[rr * 72 + 8 * kg] =
                *(const uint4*)&yT[((size_t)(b * Ll + l0 + rr)) * Hh + kk + 8 * kg];
        }
        __syncthreads();

        #pragma unroll
        for (int ks = 0; ks < 64; ks += 32) {
            const bf16x8 af = *(const bf16x8*)&Wlds[(16 * wv + l15) * 72 + ks + 8 * quad];
            const bf16x8 gf = *(const bf16x8*)&Wlds[(64 + 16 * wv + l15) * 72 + ks + 8 * quad];
            #pragma unroll
            for (int j = 0; j < 8; ++j) {
                const bf16x8 bfr = *(const bf16x8*)&Ylds[(16 * j + l15) * 72 + ks + 8 * quad];
                accA[j] = __builtin_amdgcn_mfma_f32_16x16x32_bf16(af, bfr, accA[j], 0, 0, 0);
                accG[j] = __builtin_amdgcn_mfma_f32_16x16x32_bf16(gf, bfr, accG[j], 0, 0, 0);
            }
        }
        __syncthreads();
    }

    const int mb = m0 + 16 * wv + 4 * quad;
    float bA[4], bG[4];
    #pragma unroll
    for (int rr = 0; rr < 4; ++rr) { bA[rr] = bias[mb + rr]; bG[rr] = bias[mb + rr + 512]; }

    #pragma unroll
    for (int j = 0; j < 8; ++j) {
        const int l = l0 + 16 * j + l15;
        #pragma unroll
        for (int rr = 0; rr < 4; ++rr) {
            const float a = accA[j][rr] + bA[rr];
            const float g = accG[j][rr] + bG[rr];
            out[((size_t)(b * Hh + mb + rr)) * Ll + l] = a / (1.f + expf(-g));
        }
    }
}

extern "C" void kernel_launch(void* const* d_in, const int* in_sizes, int n_in,
                              void* d_out, int out_size, void* d_ws, size_t ws_size,
                              hipStream_t stream)
{
    const float* u          = (const float*)d_in[0];
    const float* log_dt     = (const float*)d_in[1];
    const float* C_re       = (const float*)d_in[2];
    const float* C_im       = (const float*)d_in[3];
    const float* log_A_real = (const float*)d_in[4];
    const float* A_imag     = (const float*)d_in[5];
    const float* Dp         = (const float*)d_in[6];
    const float* W          = (const float*)d_in[7];
    const float* bias       = (const float*)d_in[8];

    float* out = (float*)d_out;
    float* scratch = (float*)d_out;                         // floats [8M, ...)
    unsigned short* y_bf = (unsigned short*)d_out;          // bf16 [0, 32MiB)
    unsigned short* y_T  = (unsigned short*)d_ws;           // 32 MiB
    unsigned short* Wb   = (unsigned short*)((char*)d_ws + (32u << 20)); // 1 MiB

    s4d_k1<<<dim3(Hh), dim3(256), 0, stream>>>(
        log_dt, C_re, C_im, log_A_real, A_imag, W, scratch, Wb);
    s4d_k23<<<dim3(Bb * Hh), dim3(256), 0, stream>>>(
        u, log_dt, log_A_real, A_imag, Dp, scratch, y_bf);
    s4d_T<<<dim3(Bb * Hh), dim3(256), 0, stream>>>(y_bf, y_T);
    s4d_s2<<<dim3(256, 8), dim3(256), 0, stream>>>(y_T, Wb, bias, out);
}